// Round 3
// baseline (173.156 us; speedup 1.0000x reference)
//
#include <hip/hip_runtime.h>

// Cost volume: B=4, C=32, H=256, W=256, D=9, G=8, cpg=4
// y offset is 0 => bilinear collapses to 1-D lerp along x.
// R3: VALU-bound fix.
//  - One block per (b,h); all 8 groups + all 9 d in-thread (setup amortized).
//  - Per-d 3-tap weight vectors precomputed once (validity folded in) =>
//    inner loop is pure FMA, zero cndmask.
//  - Two channels processed per float2 ext-vector => v_pk_fma_f32 dual fp32.
//  - var*3 = sum(x^2) - (sum x)^2/3 form.

#define B_ 4
#define C_ 32
#define H_ 256
#define W_ 256
#define D_ 9
#define G_ 8
#define CPG 4
#define HW_ (H_ * W_)

typedef float v2f __attribute__((ext_vector_type(2)));

__global__ __launch_bounds__(256) void cost_volume_kernel(
    const float* __restrict__ fref,
    const float* __restrict__ fls,
    const float* __restrict__ frs,
    const float* __restrict__ disp0,
    float* __restrict__ out)
{
    const float res[D_] = {-0.4f, -0.3f, -0.2f, -0.1f, 0.0f,
                            0.1f,  0.2f,  0.3f,  0.4f};
    int t = blockIdx.x;
    int h = t & (H_ - 1);
    int b = t >> 8;
    int w = threadIdx.x;

    float dbase = disp0[((size_t)b * H_ + h) * W_ + w];

    // Tap base indices. xl(d) = w + dbase + res[d] spans < 1.0 over d, so
    // floor(xl) takes at most 2 consecutive values; 3 taps cover all 9 d.
    int i0l = (int)floorf((float)w + (dbase + res[0]));
    int i0r = (int)floorf((float)w - (dbase + res[8]));

    // Validity (zeros padding) + clamped load indices, once per thread.
    float vl[3], vr[3];
    int il[3], ir[3];
    #pragma unroll
    for (int k = 0; k < 3; ++k) {
        int a = i0l + k;
        vl[k] = (a >= 0 && a < W_) ? 1.0f : 0.0f;
        il[k] = min(max(a, 0), W_ - 1);
        int c = i0r + k;
        vr[k] = (c >= 0 && c < W_) ? 1.0f : 0.0f;
        ir[k] = min(max(c, 0), W_ - 1);
    }

    // Per-d 3-tap weights with validity folded in (zero weight on OOB tap).
    float la[D_], lb[D_], lc[D_];
    float ra[D_], rb[D_], rc[D_];
    #pragma unroll
    for (int d = 0; d < D_; ++d) {
        float disp = dbase + res[d];

        float xl = (float)w + disp;
        float fl = floorf(xl);
        float w1 = xl - fl;
        float w0 = 1.0f - w1;
        bool jl = ((int)fl != i0l);       // floor offset 0 or 1
        la[d] = jl ? 0.0f : w0 * vl[0];
        lb[d] = jl ? w0 * vl[1] : w1 * vl[1];
        lc[d] = jl ? w1 * vl[2] : 0.0f;

        float xr = (float)w - disp;
        float fx = floorf(xr);
        float u1 = xr - fx;
        float u0 = 1.0f - u1;
        bool jr = ((int)fx != i0r);
        ra[d] = jr ? 0.0f : u0 * vr[0];
        rb[d] = jr ? u0 * vr[1] : u1 * vr[1];
        rc[d] = jr ? u1 * vr[2] : 0.0f;
    }

    size_t base = (size_t)b * C_ * HW_ + (size_t)h * W_;
    const float* pref = fref + base;
    const float* pls  = fls  + base;
    const float* prs  = frs  + base;

    size_t obase = (size_t)b * G_ * D_ * HW_ + (size_t)h * W_ + w;

    #pragma unroll 1
    for (int g = 0; g < G_; ++g) {
        v2f acc[D_];
        #pragma unroll
        for (int d = 0; d < D_; ++d) acc[d] = (v2f)(0.0f);

        #pragma unroll
        for (int p = 0; p < 2; ++p) {
            size_t c0 = (size_t)(g * CPG + p * 2) * HW_;
            const float* rrow = pref + c0;
            const float* lrow = pls + c0;
            const float* rsw  = prs + c0;

            v2f fr = { rrow[w],      rrow[HW_ + w] };
            v2f t0 = { lrow[il[0]],  lrow[HW_ + il[0]] };
            v2f t1 = { lrow[il[1]],  lrow[HW_ + il[1]] };
            v2f t2 = { lrow[il[2]],  lrow[HW_ + il[2]] };
            v2f u0 = { rsw[ir[0]],   rsw[HW_ + ir[0]] };
            v2f u1 = { rsw[ir[1]],   rsw[HW_ + ir[1]] };
            v2f u2 = { rsw[ir[2]],   rsw[HW_ + ir[2]] };

            v2f fr2 = fr * fr;

            #pragma unroll
            for (int d = 0; d < D_; ++d) {
                v2f wl = t0 * la[d] + t1 * lb[d] + t2 * lc[d];
                v2f wr = u0 * ra[d] + u1 * rb[d] + u2 * rc[d];
                v2f s  = wl + wr + fr;
                v2f q  = __builtin_elementwise_fma(
                             wl, wl, __builtin_elementwise_fma(wr, wr, fr2));
                acc[d] += q - s * s * (1.0f / 3.0f);
            }
        }

        // var = acc3/3 (acc holds 3*var summed over 4 ch), group mean /4:
        // but acc currently holds sum over channels of (3*var_c)? No:
        // q - s^2/3 = (sum x^2) - (sum x)^2/3 = 3*var_c. Sum over 4 ch,
        // output = mean(var) = acc/(3*4) = acc/12.
        #pragma unroll
        for (int d = 0; d < D_; ++d) {
            float v = (acc[d].x + acc[d].y) * (1.0f / 12.0f);
            out[obase + (size_t)(g * D_ + d) * HW_] = v;
        }
    }
}

extern "C" void kernel_launch(void* const* d_in, const int* in_sizes, int n_in,
                              void* d_out, int out_size, void* d_ws, size_t ws_size,
                              hipStream_t stream) {
    const float* fref  = (const float*)d_in[0];
    const float* fls   = (const float*)d_in[1];
    const float* frs   = (const float*)d_in[2];
    const float* disp0 = (const float*)d_in[3];
    float* out = (float*)d_out;

    dim3 grid(B_ * H_);
    dim3 block(W_);
    cost_volume_kernel<<<grid, block, 0, stream>>>(fref, fls, frs, disp0, out);
}

// Round 4
// 170.048 us; speedup vs baseline: 1.0183x; 1.0183x over previous
//
#include <hip/hip_runtime.h>

// Cost volume: B=4, C=32, H=256, W=256, D=9, G=8, cpg=4
// y offset is 0 => bilinear collapses to 1-D lerp along x.
// R4: latency-bound fix. R3 (all 8 groups per block, 1024 blocks) starved
// occupancy (21%, VALUBusy 26%). Split to 2 groups/block: grid 4096,
// 16384 waves, setup still amortized over 8 channels. Inner loop identical
// to R3 (precomputed per-d 3-tap weights, zero cndmask, float2 packed fp32).

#define B_ 4
#define C_ 32
#define H_ 256
#define W_ 256
#define D_ 9
#define G_ 8
#define CPG 4
#define HW_ (H_ * W_)

typedef float v2f __attribute__((ext_vector_type(2)));

__global__ __launch_bounds__(256) void cost_volume_kernel(
    const float* __restrict__ fref,
    const float* __restrict__ fls,
    const float* __restrict__ frs,
    const float* __restrict__ disp0,
    float* __restrict__ out)
{
    const float res[D_] = {-0.4f, -0.3f, -0.2f, -0.1f, 0.0f,
                            0.1f,  0.2f,  0.3f,  0.4f};
    int g2 = blockIdx.x & 3;          // which pair of groups
    int t  = blockIdx.x >> 2;
    int h  = t & (H_ - 1);
    int b  = t >> 8;
    int w  = threadIdx.x;

    float dbase = disp0[((size_t)b * H_ + h) * W_ + w];

    // Tap base indices. xl(d) = w + dbase + res[d] spans 0.8 (< 1.0) over d,
    // so floor(xl) takes at most 2 consecutive values; 3 taps cover all 9 d.
    int i0l = (int)floorf((float)w + (dbase + res[0]));
    int i0r = (int)floorf((float)w - (dbase + res[8]));

    // Validity (zeros padding) + clamped load indices, once per thread.
    float vl[3], vr[3];
    int il[3], ir[3];
    #pragma unroll
    for (int k = 0; k < 3; ++k) {
        int a = i0l + k;
        vl[k] = (a >= 0 && a < W_) ? 1.0f : 0.0f;
        il[k] = min(max(a, 0), W_ - 1);
        int c = i0r + k;
        vr[k] = (c >= 0 && c < W_) ? 1.0f : 0.0f;
        ir[k] = min(max(c, 0), W_ - 1);
    }

    // Per-d 3-tap weights with validity folded in (zero weight on OOB tap).
    float la[D_], lb[D_], lc[D_];
    float ra[D_], rb[D_], rc[D_];
    #pragma unroll
    for (int d = 0; d < D_; ++d) {
        float disp = dbase + res[d];

        float xl = (float)w + disp;
        float fl = floorf(xl);
        float w1 = xl - fl;
        float w0 = 1.0f - w1;
        bool jl = ((int)fl != i0l);       // floor offset 0 or 1
        la[d] = jl ? 0.0f : w0 * vl[0];
        lb[d] = jl ? w0 * vl[1] : w1 * vl[1];
        lc[d] = jl ? w1 * vl[2] : 0.0f;

        float xr = (float)w - disp;
        float fx = floorf(xr);
        float u1 = xr - fx;
        float u0 = 1.0f - u1;
        bool jr = ((int)fx != i0r);
        ra[d] = jr ? 0.0f : u0 * vr[0];
        rb[d] = jr ? u0 * vr[1] : u1 * vr[1];
        rc[d] = jr ? u1 * vr[2] : 0.0f;
    }

    size_t base = (size_t)b * C_ * HW_ + (size_t)h * W_;
    const float* pref = fref + base;
    const float* pls  = fls  + base;
    const float* prs  = frs  + base;

    size_t obase = (size_t)b * G_ * D_ * HW_ + (size_t)h * W_ + w;

    #pragma unroll 1
    for (int gi = 0; gi < 2; ++gi) {
        int g = g2 * 2 + gi;
        v2f acc[D_];
        #pragma unroll
        for (int d = 0; d < D_; ++d) acc[d] = (v2f)(0.0f);

        #pragma unroll
        for (int p = 0; p < 2; ++p) {
            size_t c0 = (size_t)(g * CPG + p * 2) * HW_;
            const float* rrow = pref + c0;
            const float* lrow = pls + c0;
            const float* rsw  = prs + c0;

            v2f fr = { rrow[w],      rrow[HW_ + w] };
            v2f t0 = { lrow[il[0]],  lrow[HW_ + il[0]] };
            v2f t1 = { lrow[il[1]],  lrow[HW_ + il[1]] };
            v2f t2 = { lrow[il[2]],  lrow[HW_ + il[2]] };
            v2f u0 = { rsw[ir[0]],   rsw[HW_ + ir[0]] };
            v2f u1 = { rsw[ir[1]],   rsw[HW_ + ir[1]] };
            v2f u2 = { rsw[ir[2]],   rsw[HW_ + ir[2]] };

            v2f fr2 = fr * fr;

            #pragma unroll
            for (int d = 0; d < D_; ++d) {
                v2f wl = t0 * la[d] + t1 * lb[d] + t2 * lc[d];
                v2f wr = u0 * ra[d] + u1 * rb[d] + u2 * rc[d];
                v2f s  = wl + wr + fr;
                v2f q  = __builtin_elementwise_fma(
                             wl, wl, __builtin_elementwise_fma(wr, wr, fr2));
                acc[d] += q - s * s * (1.0f / 3.0f);
            }
        }

        // q - s^2/3 = sum(x^2) - (sum x)^2/3 = 3*var_c. Summed over 4 ch,
        // output = mean(var) = acc / (3*4) = acc/12.
        #pragma unroll
        for (int d = 0; d < D_; ++d) {
            float v = (acc[d].x + acc[d].y) * (1.0f / 12.0f);
            out[obase + (size_t)(g * D_ + d) * HW_] = v;
        }
    }
}

extern "C" void kernel_launch(void* const* d_in, const int* in_sizes, int n_in,
                              void* d_out, int out_size, void* d_ws, size_t ws_size,
                              hipStream_t stream) {
    const float* fref  = (const float*)d_in[0];
    const float* fls   = (const float*)d_in[1];
    const float* frs   = (const float*)d_in[2];
    const float* disp0 = (const float*)d_in[3];
    float* out = (float*)d_out;

    dim3 grid(B_ * H_ * 4);
    dim3 block(W_);
    cost_volume_kernel<<<grid, block, 0, stream>>>(fref, fls, frs, disp0, out);
}